// Round 6
// baseline (24036.845 us; speedup 1.0000x reference)
//
#include <hip/hip_runtime.h>
#include <hip/hip_bf16.h>
#include <stdint.h>

// Problem: IN=512, H=2048, OUT=512, T=8192. Gate rows 4H=8192.
// Persistent-RNN: 256 blocks x 256 threads (4 waves), 1 block/CU, [W_ih|W_hh]
// in VGPRs as f16 pairs (160 u32/lane). h exchanged device-wide as
// step-tagged u64 ({f16 pair | step}) via L3, sc0 sc1 asm polls.
// Round 16 = r13 (14.35ms champion) with h-dot REVERTED to dot2 (r15 lesson)
// + ONE structural change: in-loop __syncthreads -> r11's quarter-flag
// protocol with per-wave ROTATED quarter order.
//   - r15 POST-MORTEM: pk_fma_f16 regressed (+160cy = +40 instrs x ~4cy).
//     dot2 and pk_fma issue at the SAME rate; instruction count is the VALU
//     cost; 128 dot2 is the floor. The dot-rate lever is exhausted.
//   - Quarter flags (correctness HW-PROVEN by r11's passing run; its 43ms
//     was the stale-L1 atomic polls, fixed in r12): wave q stages its
//     quarter, lgkmcnt(0), sets qflag[bs][q]=s; consumers gate each quarter
//     of the h-dot on its flag. Safety: staging parity P at step s requires
//     watched blocks at s-1 => (transitively, via their 4 waves' disjoint
//     quarters covering ALL blocks) all blocks published s-2 => every
//     same-block wave finished step s-2's h-dot on parity P.
//   - Rotation: wave q runs h-dot quarters in order q, q+1, q+2, q+3 (own
//     first, NO wait — it just staged it). Each later flag is needed ~140cy
//     deeper into the dot => inter-wave skew absorbed under work instead of
//     serialized at a barrier. Wave-uniform branch, literal j (rule #20).
// r14 POST-MORTEM (crash): never exit a spin with un-waited loads; single
//   poll set, all exits via vmcnt(0).
// r11 POST-MORTEM: __hip_atomic_load(RELAXED,AGENT) does NOT emit sc0 ->
//   stale L1 polls. Spin must use asm global_load_dwordx4 sc0 sc1.
// Register-budget law (r7/r9): arch VGPRs cap at 256/wave. 160 weight regs
//   fit ONLY with 256-thread blocks; no 512-thread or 320-reg variants.

// ---------------- helpers ----------------

__device__ __forceinline__ uint32_t packf16(float a, float b) {
    // v_cvt_pkrtz_f16_f32: a -> low16, b -> high16 (RTZ)
    auto h = __builtin_amdgcn_cvt_pkrtz(a, b);
    return __builtin_bit_cast(uint32_t, h);
}

__device__ __forceinline__ float dot2h(uint32_t a, uint32_t b, float c) {
    float d;
    asm("v_dot2_f32_f16 %0, %1, %2, %3" : "=v"(d) : "v"(a), "v"(b), "v"(c));
    return d;
}

template <int CTRL>
__device__ __forceinline__ float movdpp(float x) {
    return __int_as_float(__builtin_amdgcn_mov_dpp(__float_as_int(x), CTRL, 0xF, 0xF, true));
}

// acc += shfl_xor(acc,16) via v_permlane16_swap (a'={r0,r0,r2,r2}, b'={r1,r1,r3,r3})
__device__ __forceinline__ float xorsum16(float x) {
#if __has_builtin(__builtin_amdgcn_permlane16_swap)
    auto r = __builtin_amdgcn_permlane16_swap(__float_as_uint(x), __float_as_uint(x), false, false);
    return __uint_as_float(r[0]) + __uint_as_float(r[1]);
#else
    return x + __shfl_xor(x, 16, 64);
#endif
}

// acc += shfl_xor(acc,32) via v_permlane32_swap (a'={lo,lo}, b'={hi,hi})
__device__ __forceinline__ float xorsum32(float x) {
#if __has_builtin(__builtin_amdgcn_permlane32_swap)
    auto r = __builtin_amdgcn_permlane32_swap(__float_as_uint(x), __float_as_uint(x), false, false);
    return __uint_as_float(r[0]) + __uint_as_float(r[1]);
#else
    return x + __shfl_xor(x, 32, 64);
#endif
}

__device__ __forceinline__ float sigm(float x) { return 1.f / (1.f + __expf(-x)); }
__device__ __forceinline__ float tanh_fast(float x) { return 1.f - 2.f / (1.f + __expf(2.f * x)); }

#define ASTORE(p, v) __hip_atomic_store((p), (v), __ATOMIC_RELAXED, __HIP_MEMORY_SCOPE_AGENT)
#define LDS_ST(p, v) __hip_atomic_store((p), (v), __ATOMIC_RELAXED, __HIP_MEMORY_SCOPE_WORKGROUP)
#define LDS_LDACQ(p) __hip_atomic_load((p), __ATOMIC_ACQUIRE, __HIP_MEMORY_SCOPE_WORKGROUP)

// Issue two 16B device-scope loads (bypass L1/L2 via sc0 sc1), NO wait.
// Tear-safe: each contained u64 carries its own tag in the low 32 bits.
__device__ __forceinline__ void poll_issue(const unsigned long long* pa,
                                           const unsigned long long* pb,
                                           ulonglong2& ra, ulonglong2& rb) {
    asm volatile(
        "global_load_dwordx4 %0, %2, off sc0 sc1\n\t"
        "global_load_dwordx4 %1, %3, off sc0 sc1"
        : "=v"(ra), "=v"(rb)
        : "v"(pa), "v"(pb)
        : "memory");
    __builtin_amdgcn_sched_barrier(0);  // keep dependent VALU below the issue
}

__device__ __forceinline__ void poll_wait() {
    asm volatile("s_waitcnt vmcnt(0)" ::: "memory");
    __builtin_amdgcn_sched_barrier(0);  // rule #18: stop reg-only hoisting past waitcnt
}

// ---------------- kernel 0: invalidate tags ----------------
__global__ __launch_bounds__(256) void init_hbuf(unsigned long long* hbuf) {
    int i = blockIdx.x * 256 + threadIdx.x;
    if (i < 2048) hbuf[i] = ~0ull;  // tag 0xFFFFFFFF never matches a step index
}

// ---------------- kernel 1: persistent LSTM recurrence ----------------
// Block b owns h indices [8b, 8b+8). Wave q owns rows {hb+2q, hb+2q+1}, ALL 4
// gates (combo c = gate*2 + rowbit). Weights: 160 packed f16 VGPRs/lane
// (k<4 = W_ih, else W_hh remapped: w[c*20+4+4j+i] <-> h pair 256j+4*lane+i).
// Spin: wave q polls pairs [256q,256q+256): lane L watches pairs {256q+2L,
// 256q+2L+1} and {256q+128+2L, +1} via 2 dwordx4.
__global__ __launch_bounds__(256, 1) void lstm_persist(const float* __restrict__ seq,
                                                       const float* __restrict__ Wih,
                                                       const float* __restrict__ Whh,
                                                       const float* __restrict__ bih,
                                                       const float* __restrict__ bhh,
                                                       const float* __restrict__ h0,
                                                       const float* __restrict__ c0,
                                                       unsigned long long* hbuf,
                                                       float* __restrict__ hf32) {
    const int b = blockIdx.x, tid = threadIdx.x;
    const int q = tid >> 6, lane = tid & 63;
    const int hb = b * 8;
    const int rb = (lane >> 2) & 1;       // this lane's row within the wave's pair
    const int myrow = hb + 2 * q + rb;

    // ---- preload [W_ih | W_hh] rows for all 4 gates of rows {2q, 2q+1} ----
    uint32_t w[160];
#pragma unroll
    for (int c = 0; c < 8; c++) {
        const int R = (c >> 1) * 2048 + hb + 2 * q + (c & 1);
        const float2* rih = (const float2*)(Wih + (size_t)R * 512);
        const float2* rhh = (const float2*)(Whh + (size_t)R * 2048);
#pragma unroll
        for (int k = 0; k < 4; k++) {
            float2 v = rih[k * 64 + lane];
            w[c * 20 + k] = packf16(v.x, v.y);
        }
        // W_hh remap to match the b128 h-dot: w[c*20+4+4j+i] <-> h pair 256j+4*lane+i
#pragma unroll
        for (int j = 0; j < 4; j++)
#pragma unroll
            for (int i = 0; i < 4; i++) {
                float2 v = rhh[256 * j + 4 * lane + i];
                w[c * 20 + 4 + 4 * j + i] = packf16(v.x, v.y);
            }
    }

    __shared__ alignas(16) uint32_t v_stage[2][1024];  // h_{t-1} pairs, parity dbuf
    __shared__ alignas(16) uint32_t qflag[2][4];       // per-(parity, quarter) step tag
    if (tid < 8) ((uint32_t*)qflag)[tid] = 0;          // 0 never matches su>=1

    // per-lane (replicated) bias + c state for row `myrow`
    const float bi  = bih[myrow] + bhh[myrow];
    const float bf_ = bih[2048 + myrow] + bhh[2048 + myrow];
    const float bg  = bih[4096 + myrow] + bhh[4096 + myrow];
    const float bo  = bih[6144 + myrow] + bhh[6144 + myrow];
    float c_state = c0[myrow];

    // publish h0 slice with tag 0 (parity 0)
    if (q == 0 && lane < 4) {
        float a = h0[hb + lane * 2], b2 = h0[hb + lane * 2 + 1];
        unsigned long long v = ((unsigned long long)packf16(a, b2) << 32);
        ASTORE(&hbuf[b * 4 + lane], v);
    }

    // prefetch x_0: lane owns x pairs {k*64+lane : k in [0,4)}
    float2 xn[4];
#pragma unroll
    for (int k = 0; k < 4; k++) xn[k] = ((const float2*)seq)[k * 64 + lane];

    __syncthreads();  // qflag init visible — the ONLY barrier in the kernel

    int gave_up = 0;

// wait for quarter jj's flag to reach this step (acquire orders later ds reads)
#define HQ_WAIT(jj)                                                                       \
    {                                                                                     \
        uint32_t fj = LDS_LDACQ(&qflag[bs][(jj)]);                                        \
        if (fj != su) {                                                                   \
            int zz = 0;                                                                   \
            do { fj = LDS_LDACQ(&qflag[bs][(jj)]); } while (fj != su && ++zz < (1 << 20)); \
        }                                                                                 \
        __builtin_amdgcn_sched_barrier(0);                                                \
    }

// accumulate quarter jj of the h-dot (literal jj => static w[] indexing)
#define HQ_DOT(jj)                                                                        \
    {                                                                                     \
        const uint4 hv = *(const uint4*)&v_stage[bs][256 * (jj) + 4 * lane];              \
        _Pragma("unroll")                                                                 \
        for (int c = 0; c < 8; c++) {                                                     \
            float a = dot2h(w[c * 20 + 4 + 4 * (jj) + 0], hv.x, acc[c]);                  \
            a = dot2h(w[c * 20 + 4 + 4 * (jj) + 1], hv.y, a);                             \
            a = dot2h(w[c * 20 + 4 + 4 * (jj) + 2], hv.z, a);                             \
            acc[c] = dot2h(w[c * 20 + 4 + 4 * (jj) + 3], hv.w, a);                        \
        }                                                                                 \
    }

    for (int s = 1; s <= 8192; s++) {
        const int t = s - 1, bs = t & 1;
        const uint32_t want = (uint32_t)t;

        // ---- pack x_t (compiler drains the x prefetch here, BEFORE poll issue) ----
        uint32_t x0 = packf16(xn[0].x, xn[0].y), x1 = packf16(xn[1].x, xn[1].y);
        uint32_t x2 = packf16(xn[2].x, xn[2].y), x3 = packf16(xn[3].x, xn[3].y);
        __builtin_amdgcn_sched_barrier(0);  // pin pack (and its waitcnt) above poll issue

        // ---- early poll issue: first sweep's RTT overlaps the x-dot ----
        const unsigned long long* base = hbuf + (bs << 10) + q * 256;
        const unsigned long long* pa = base + 2 * lane;        // pairs 2L, 2L+1
        const unsigned long long* pb = base + 128 + 2 * lane;  // pairs 128+2L, +1
        ulonglong2 ra, rb2;
        poll_issue(pa, pb, ra, rb2);

        // ---- x-part of dot from registers (VALU-only, hides first poll RTT) ----
        float acc[8];
#pragma unroll
        for (int c = 0; c < 8; c++) {
            float a = dot2h(w[c * 20 + 0], x0, 0.f);
            a = dot2h(w[c * 20 + 1], x1, a);
            a = dot2h(w[c * 20 + 2], x2, a);
            acc[c] = dot2h(w[c * 20 + 3], x3, a);
        }

        // ---- distributed spin: wave q owns pairs [256q, 256q+256) ----
        if (!gave_up) {
            int tries = 0;
            for (;;) {
                poll_wait();
                int ok = ((uint32_t)ra.x == want) & ((uint32_t)ra.y == want) &
                         ((uint32_t)rb2.x == want) & ((uint32_t)rb2.y == want);
                if (__all(ok)) break;
                if (++tries > (1 << 17)) { gave_up = 1; break; }  // diagnostic fuse
                poll_issue(pa, pb, ra, rb2);                      // reissue first...
                if (tries > 2) __builtin_amdgcn_s_sleep(1);       // ...sleep overlaps RTT
            }
        } else {
            poll_wait();  // loop-top issue acts as the once-per-iter refresh
        }

        // ---- stage payload -> LDS, then release this quarter's flag ----
        {
            uint2* vsa = (uint2*)&v_stage[bs][q * 256 + 2 * lane];
            uint2* vsb = (uint2*)&v_stage[bs][q * 256 + 128 + 2 * lane];
            *vsa = make_uint2((uint32_t)(ra.x >> 32), (uint32_t)(ra.y >> 32));
            *vsb = make_uint2((uint32_t)(rb2.x >> 32), (uint32_t)(rb2.y >> 32));
            asm volatile("s_waitcnt lgkmcnt(0)" ::: "memory");  // payload landed in LDS
            __builtin_amdgcn_sched_barrier(0);
            if (lane == 0) LDS_ST(&qflag[bs][q], (uint32_t)s);
        }

        // prefetch x_{t+1}: drains under the h-dot (no barrier, no forced drain)
        if (s < 8192) {
            const float2* xp = (const float2*)(seq + (size_t)s * 512);
#pragma unroll
            for (int k = 0; k < 4; k++) xn[k] = xp[k * 64 + lane];
        }

        // ---- h-part of dot: 4 quarters x b128, rotated: own quarter FIRST
        // (no wait — we just staged it), then cyclic. Each later flag is
        // needed ~140cy deeper into the dot => skew absorbed under work.
        // Wave-uniform branch; literal quarter indices (rule #20). ----
        const uint32_t su = (uint32_t)s;
        if (q == 0) {
            HQ_DOT(0); HQ_WAIT(1) HQ_DOT(1); HQ_WAIT(2) HQ_DOT(2); HQ_WAIT(3) HQ_DOT(3);
        } else if (q == 1) {
            HQ_DOT(1); HQ_WAIT(2) HQ_DOT(2); HQ_WAIT(3) HQ_DOT(3); HQ_WAIT(0) HQ_DOT(0);
        } else if (q == 2) {
            HQ_DOT(2); HQ_WAIT(3) HQ_DOT(3); HQ_WAIT(0) HQ_DOT(0); HQ_WAIT(1) HQ_DOT(1);
        } else {
            HQ_DOT(3); HQ_WAIT(0) HQ_DOT(0); HQ_WAIT(1) HQ_DOT(1); HQ_WAIT(2) HQ_DOT(2);
        }

        // ---- fold 8 accs -> 1; DPP/permlane forms (only xor4 keeps DS).
        // Lane L holds combo c(L&7) = 4*(L&1) + 2*((L>>1)&1) + ((L>>2)&1),
        // replicated every 8 lanes ----
#pragma unroll
        for (int j = 0; j < 4; j++) {  // d=1: 8 -> 4 (quad_perm xor1 = 0xB1)
            float lo = acc[j], hi = acc[j + 4];
            float sel = (lane & 1) ? lo : hi;
            float got = movdpp<0xB1>(sel);
            acc[j] = ((lane & 1) ? hi : lo) + got;
        }
#pragma unroll
        for (int j = 0; j < 2; j++) {  // d=2: 4 -> 2 (quad_perm xor2 = 0x4E)
            float lo = acc[j], hi = acc[j + 2];
            float sel = (lane & 2) ? lo : hi;
            float got = movdpp<0x4E>(sel);
            acc[j] = ((lane & 2) ? hi : lo) + got;
        }
        {  // d=4: 2 -> 1 (no DPP form for xor4; keep ds shuffle)
            float lo = acc[0], hi = acc[1];
            float sel = (lane & 4) ? lo : hi;
            float got = __shfl_xor(sel, 4, 64);
            acc[0] = ((lane & 4) ? hi : lo) + got;
        }
        acc[0] += movdpp<0x128>(acc[0]);  // xor8 via row_ror:8
        acc[0] = xorsum16(acc[0]);        // xor16 via permlane16_swap
        acc[0] = xorsum32(acc[0]);        // xor32 via permlane32_swap

        // combo layout within each 4-lane group (quad base):
        // +0: i(row rb), +1: g, +2: f, +3: o  (rb = (lane>>2)&1)
        float gi = movdpp<0x00>(acc[0]);  // quad bcast lane0
        float gg = movdpp<0x55>(acc[0]);  // quad bcast lane1
        float gf = movdpp<0xAA>(acc[0]);  // quad bcast lane2
        float go = movdpp<0xFF>(acc[0]);  // quad bcast lane3
        float i_ = sigm(gi + bi), f_ = sigm(gf + bf_), g_ = tanh_fast(gg + bg), o_ = sigm(go + bo);
        c_state = f_ * c_state + i_ * g_;
        float hval = o_ * tanh_fast(c_state);  // lanes 0-3: row0, lanes 4-7: row1 (replicated)

        // h1 (a row1 value) into lane 0 via row_ror:4
        float h1 = movdpp<0x124>(hval);
        if (lane == 0) {
            unsigned long long v = ((unsigned long long)packf16(hval, h1) << 32) | (uint32_t)s;
            ASTORE(&hbuf[((s & 1) << 10) + b * 4 + q], v);
            if (s == 8192) { hf32[hb + 2 * q] = hval; hf32[hb + 2 * q + 1] = h1; }
        }
    }
#undef HQ_WAIT
#undef HQ_DOT
}

// ---------------- kernel 2: pred = h_last @ W_lin^T + b_lin ----------------
__global__ __launch_bounds__(256) void final_linear(const float* __restrict__ hf,
                                                    const float* __restrict__ Wlin,
                                                    const float* __restrict__ blin,
                                                    float* __restrict__ out) {
    const int row = blockIdx.x * 4 + (threadIdx.x >> 6);
    const int lane = threadIdx.x & 63;
    float acc = 0.f;
#pragma unroll
    for (int it = 0; it < 8; it++) {
        int c = it * 256 + lane * 4;
        float4 wv = *(const float4*)&Wlin[(size_t)row * 2048 + c];
        float4 hv = *(const float4*)&hf[c];
        acc += wv.x * hv.x + wv.y * hv.y + wv.z * hv.z + wv.w * hv.w;
    }
#pragma unroll
    for (int off = 32; off; off >>= 1) acc += __shfl_xor(acc, off, 64);
    if (lane == 0) out[row] = acc + blin[row];
}

// ---------------- launch ----------------
extern "C" void kernel_launch(void* const* d_in, const int* in_sizes, int n_in,
                              void* d_out, int out_size, void* d_ws, size_t ws_size,
                              hipStream_t stream) {
    const float* seq  = (const float*)d_in[0];
    const float* Wih  = (const float*)d_in[1];
    const float* Whh  = (const float*)d_in[2];
    const float* bih  = (const float*)d_in[3];
    const float* bhh  = (const float*)d_in[4];
    const float* h0   = (const float*)d_in[5];
    const float* c0   = (const float*)d_in[6];
    const float* Wlin = (const float*)d_in[7];
    const float* blin = (const float*)d_in[8];
    float* out = (float*)d_out;

    char* ws = (char*)d_ws;
    unsigned long long* hbuf = (unsigned long long*)ws;  // 2*1024*8 = 16 KiB
    float* hf32 = (float*)(ws + 16384);                  // 8 KiB

    init_hbuf<<<8, 256, 0, stream>>>(hbuf);
    lstm_persist<<<256, 256, 0, stream>>>(seq, Wih, Whh, bih, bhh, h0, c0, hbuf, hf32);
    final_linear<<<128, 256, 0, stream>>>(hf32, Wlin, blin, out);
}

// Round 7
// 13975.006 us; speedup vs baseline: 1.7200x; 1.7200x over previous
//
#include <hip/hip_runtime.h>
#include <hip/hip_bf16.h>
#include <stdint.h>

// Problem: IN=512, H=2048, OUT=512, T=8192. Gate rows 4H=8192.
// Persistent-RNN: 256 blocks x 256 threads (4 waves), 1 block/CU, [W_ih|W_hh]
// in VGPRs as f16 pairs (160 u32/lane). h exchanged device-wide as
// step-tagged u64 ({f16 pair | step}) via L3, sc0 sc1 asm polls.
// Round 17 = r13 champion (14.35ms) + ONE spin-internal change: STICKY-HALF
// polling. Poll traffic is 1024 waves x 2KB per ~600cy sweep ~= 8 TB/s of L3
// traffic (same order as Infinity Cache BW; r4 history shows congestion
// collapse at ~3x this). Tags are monotonic within a step (tag==want =>
// payload final), so each lane stops re-loading a 16B half once both its
// u64 tags matched and reissues only unmatched halves => ~30-50% less poll
// traffic, deflating RTT+jitter device-wide. Spin invariants kept: every
// sweep begins s_waitcnt vmcnt(0); NO exit with un-waited loads (r14 law);
// in-loop __syncthreads kept (r16 law below).
// r16 POST-MORTEM (+68%): quarter-flag/rotated h-dot spread per-block publish
//   times; step time = max over 256 blocks and the variance feeds forward.
//   Publish lockstep via the in-loop barrier is LOAD-BEARING. Flag family
//   closed. r15: dot2 and pk_fma issue at same rate; 128 dot2 is the VALU
//   floor; dot-rate lever closed. r14: pipelined 2-set polls crashed (VMEM
//   writeback into freed regs); closed.
// r11 POST-MORTEM: __hip_atomic_load(RELAXED,AGENT) does NOT emit sc0 ->
//   stale L1 polls. Spin must use asm global_load_dwordx4 sc0 sc1.
// Register-budget law (r7/r9): arch VGPRs cap at 256/wave. 160 weight regs
//   fit ONLY with 256-thread blocks; no 512-thread or 320-reg variants.

// ---------------- helpers ----------------

__device__ __forceinline__ uint32_t packf16(float a, float b) {
    // v_cvt_pkrtz_f16_f32: a -> low16, b -> high16 (RTZ)
    auto h = __builtin_amdgcn_cvt_pkrtz(a, b);
    return __builtin_bit_cast(uint32_t, h);
}

__device__ __forceinline__ float dot2h(uint32_t a, uint32_t b, float c) {
    float d;
    asm("v_dot2_f32_f16 %0, %1, %2, %3" : "=v"(d) : "v"(a), "v"(b), "v"(c));
    return d;
}

template <int CTRL>
__device__ __forceinline__ float movdpp(float x) {
    return __int_as_float(__builtin_amdgcn_mov_dpp(__float_as_int(x), CTRL, 0xF, 0xF, true));
}

// acc += shfl_xor(acc,16) via v_permlane16_swap (a'={r0,r0,r2,r2}, b'={r1,r1,r3,r3})
__device__ __forceinline__ float xorsum16(float x) {
#if __has_builtin(__builtin_amdgcn_permlane16_swap)
    auto r = __builtin_amdgcn_permlane16_swap(__float_as_uint(x), __float_as_uint(x), false, false);
    return __uint_as_float(r[0]) + __uint_as_float(r[1]);
#else
    return x + __shfl_xor(x, 16, 64);
#endif
}

// acc += shfl_xor(acc,32) via v_permlane32_swap (a'={lo,lo}, b'={hi,hi})
__device__ __forceinline__ float xorsum32(float x) {
#if __has_builtin(__builtin_amdgcn_permlane32_swap)
    auto r = __builtin_amdgcn_permlane32_swap(__float_as_uint(x), __float_as_uint(x), false, false);
    return __uint_as_float(r[0]) + __uint_as_float(r[1]);
#else
    return x + __shfl_xor(x, 32, 64);
#endif
}

__device__ __forceinline__ float sigm(float x) { return 1.f / (1.f + __expf(-x)); }
__device__ __forceinline__ float tanh_fast(float x) { return 1.f - 2.f / (1.f + __expf(2.f * x)); }

#define ASTORE(p, v) __hip_atomic_store((p), (v), __ATOMIC_RELAXED, __HIP_MEMORY_SCOPE_AGENT)

// Issue two 16B device-scope loads (bypass L1/L2 via sc0 sc1), NO wait.
// Tear-safe: each contained u64 carries its own tag in the low 32 bits.
__device__ __forceinline__ void poll_issue(const unsigned long long* pa,
                                           const unsigned long long* pb,
                                           ulonglong2& ra, ulonglong2& rb) {
    asm volatile(
        "global_load_dwordx4 %0, %2, off sc0 sc1\n\t"
        "global_load_dwordx4 %1, %3, off sc0 sc1"
        : "=v"(ra), "=v"(rb)
        : "v"(pa), "v"(pb)
        : "memory");
    __builtin_amdgcn_sched_barrier(0);  // keep dependent VALU below the issue
}

// Reissue a single 16B half (used by the sticky spin on unmatched halves only).
__device__ __forceinline__ void poll_issue_one(const unsigned long long* p, ulonglong2& r) {
    asm volatile("global_load_dwordx4 %0, %1, off sc0 sc1"
                 : "=v"(r) : "v"(p) : "memory");
}

__device__ __forceinline__ void poll_wait() {
    asm volatile("s_waitcnt vmcnt(0)" ::: "memory");
    __builtin_amdgcn_sched_barrier(0);  // rule #18: stop reg-only hoisting past waitcnt
}

// ---------------- kernel 0: invalidate tags ----------------
__global__ __launch_bounds__(256) void init_hbuf(unsigned long long* hbuf) {
    int i = blockIdx.x * 256 + threadIdx.x;
    if (i < 2048) hbuf[i] = ~0ull;  // tag 0xFFFFFFFF never matches a step index
}

// ---------------- kernel 1: persistent LSTM recurrence ----------------
// Block b owns h indices [8b, 8b+8). Wave q owns rows {hb+2q, hb+2q+1}, ALL 4
// gates (combo c = gate*2 + rowbit). Weights: 160 packed f16 VGPRs/lane
// (k<4 = W_ih, else W_hh remapped: w[c*20+4+4j+i] <-> h pair 256j+4*lane+i).
// Spin: wave q polls pairs [256q,256q+256): lane L watches pairs {256q+2L,
// 256q+2L+1} and {256q+128+2L, +1} via 2 dwordx4, sticky per-half.
__global__ __launch_bounds__(256, 1) void lstm_persist(const float* __restrict__ seq,
                                                       const float* __restrict__ Wih,
                                                       const float* __restrict__ Whh,
                                                       const float* __restrict__ bih,
                                                       const float* __restrict__ bhh,
                                                       const float* __restrict__ h0,
                                                       const float* __restrict__ c0,
                                                       unsigned long long* hbuf,
                                                       float* __restrict__ hf32) {
    const int b = blockIdx.x, tid = threadIdx.x;
    const int q = tid >> 6, lane = tid & 63;
    const int hb = b * 8;
    const int rb = (lane >> 2) & 1;       // this lane's row within the wave's pair
    const int myrow = hb + 2 * q + rb;

    // ---- preload [W_ih | W_hh] rows for all 4 gates of rows {2q, 2q+1} ----
    uint32_t w[160];
#pragma unroll
    for (int c = 0; c < 8; c++) {
        const int R = (c >> 1) * 2048 + hb + 2 * q + (c & 1);
        const float2* rih = (const float2*)(Wih + (size_t)R * 512);
        const float2* rhh = (const float2*)(Whh + (size_t)R * 2048);
#pragma unroll
        for (int k = 0; k < 4; k++) {
            float2 v = rih[k * 64 + lane];
            w[c * 20 + k] = packf16(v.x, v.y);
        }
        // W_hh remap to match the b128 h-dot: w[c*20+4+4j+i] <-> h pair 256j+4*lane+i
#pragma unroll
        for (int j = 0; j < 4; j++)
#pragma unroll
            for (int i = 0; i < 4; i++) {
                float2 v = rhh[256 * j + 4 * lane + i];
                w[c * 20 + 4 + 4 * j + i] = packf16(v.x, v.y);
            }
    }

    __shared__ alignas(16) uint32_t v_stage[2][1024];  // h_{t-1} pairs, parity double-buffered

    // per-lane (replicated) bias + c state for row `myrow`
    const float bi  = bih[myrow] + bhh[myrow];
    const float bf_ = bih[2048 + myrow] + bhh[2048 + myrow];
    const float bg  = bih[4096 + myrow] + bhh[4096 + myrow];
    const float bo  = bih[6144 + myrow] + bhh[6144 + myrow];
    float c_state = c0[myrow];

    // publish h0 slice with tag 0 (parity 0)
    if (q == 0 && lane < 4) {
        float a = h0[hb + lane * 2], b2 = h0[hb + lane * 2 + 1];
        unsigned long long v = ((unsigned long long)packf16(a, b2) << 32);
        ASTORE(&hbuf[b * 4 + lane], v);
    }

    // prefetch x_0: lane owns x pairs {k*64+lane : k in [0,4)}
    float2 xn[4];
#pragma unroll
    for (int k = 0; k < 4; k++) xn[k] = ((const float2*)seq)[k * 64 + lane];

    int gave_up = 0;

    for (int s = 1; s <= 8192; s++) {
        const int t = s - 1, bs = t & 1;
        const uint32_t want = (uint32_t)t;

        // ---- pack x_t (compiler drains the x prefetch here, BEFORE poll issue) ----
        uint32_t x0 = packf16(xn[0].x, xn[0].y), x1 = packf16(xn[1].x, xn[1].y);
        uint32_t x2 = packf16(xn[2].x, xn[2].y), x3 = packf16(xn[3].x, xn[3].y);
        __builtin_amdgcn_sched_barrier(0);  // pin pack (and its waitcnt) above poll issue

        // ---- early poll issue: first sweep's RTT overlaps the x-dot ----
        const unsigned long long* base = hbuf + (bs << 10) + q * 256;
        const unsigned long long* pa = base + 2 * lane;        // pairs 2L, 2L+1
        const unsigned long long* pb = base + 128 + 2 * lane;  // pairs 128+2L, +1
        ulonglong2 ra, rb2;
        poll_issue(pa, pb, ra, rb2);

        // ---- x-part of dot from registers (VALU-only, hides first poll RTT) ----
        float acc[8];
#pragma unroll
        for (int c = 0; c < 8; c++) {
            float a = dot2h(w[c * 20 + 0], x0, 0.f);
            a = dot2h(w[c * 20 + 1], x1, a);
            a = dot2h(w[c * 20 + 2], x2, a);
            acc[c] = dot2h(w[c * 20 + 3], x3, a);
        }

        // ---- distributed spin, sticky halves: once a 16B half's two tags
        // match (monotonic within the step), stop re-loading it; reissue
        // only unmatched halves => ~30-50% less L3 poll traffic. Every
        // sweep starts with vmcnt(0); no exit with un-waited loads. ----
        if (!gave_up) {
            int tries = 0;
            bool oka = false, okb = false;
            for (;;) {
                poll_wait();
                oka = oka | (((uint32_t)ra.x == want) & ((uint32_t)ra.y == want));
                okb = okb | (((uint32_t)rb2.x == want) & ((uint32_t)rb2.y == want));
                if (__all(oka & okb)) break;
                if (++tries > (1 << 17)) { gave_up = 1; break; }  // diagnostic fuse
                if (!oka) poll_issue_one(pa, ra);                 // reissue misses only
                if (!okb) poll_issue_one(pb, rb2);
                __builtin_amdgcn_sched_barrier(0);
                if (tries > 2) __builtin_amdgcn_s_sleep(1);       // sleep overlaps RTT
            }
        } else {
            poll_wait();  // loop-top issue acts as the once-per-iter refresh
        }

        // ---- stage payload -> LDS (identity pair layout: two b64 stores) ----
        {
            uint2* vsa = (uint2*)&v_stage[bs][q * 256 + 2 * lane];
            uint2* vsb = (uint2*)&v_stage[bs][q * 256 + 128 + 2 * lane];
            *vsa = make_uint2((uint32_t)(ra.x >> 32), (uint32_t)(ra.y >> 32));
            *vsb = make_uint2((uint32_t)(rb2.x >> 32), (uint32_t)(rb2.y >> 32));
        }

        __syncthreads();  // B1: v_stage[bs] ready (cheap: nothing in vmcnt)

        // prefetch x_{t+1} AFTER the barrier: drains under the h-dot,
        // off both the spin path and the barrier's vmcnt(0) drain.
        if (s < 8192) {
            const float2* xp = (const float2*)(seq + (size_t)s * 512);
#pragma unroll
            for (int k = 0; k < 4; k++) xn[k] = xp[k * 64 + lane];
        }

        // ---- h-part of dot: 4 quarters x b128; lane L reads pairs 256j+4L+{0..3} ----
#pragma unroll
        for (int j = 0; j < 4; j++) {
            const uint4 hv = *(const uint4*)&v_stage[bs][256 * j + 4 * lane];
#pragma unroll
            for (int c = 0; c < 8; c++) {
                float a = dot2h(w[c * 20 + 4 + 4 * j + 0], hv.x, acc[c]);
                a = dot2h(w[c * 20 + 4 + 4 * j + 1], hv.y, a);
                a = dot2h(w[c * 20 + 4 + 4 * j + 2], hv.z, a);
                acc[c] = dot2h(w[c * 20 + 4 + 4 * j + 3], hv.w, a);
            }
        }

        // ---- fold 8 accs -> 1; DPP/permlane forms (only xor4 keeps DS).
        // Lane L holds combo c(L&7) = 4*(L&1) + 2*((L>>1)&1) + ((L>>2)&1),
        // replicated every 8 lanes ----
#pragma unroll
        for (int j = 0; j < 4; j++) {  // d=1: 8 -> 4 (quad_perm xor1 = 0xB1)
            float lo = acc[j], hi = acc[j + 4];
            float sel = (lane & 1) ? lo : hi;
            float got = movdpp<0xB1>(sel);
            acc[j] = ((lane & 1) ? hi : lo) + got;
        }
#pragma unroll
        for (int j = 0; j < 2; j++) {  // d=2: 4 -> 2 (quad_perm xor2 = 0x4E)
            float lo = acc[j], hi = acc[j + 2];
            float sel = (lane & 2) ? lo : hi;
            float got = movdpp<0x4E>(sel);
            acc[j] = ((lane & 2) ? hi : lo) + got;
        }
        {  // d=4: 2 -> 1 (no DPP form for xor4; keep ds shuffle)
            float lo = acc[0], hi = acc[1];
            float sel = (lane & 4) ? lo : hi;
            float got = __shfl_xor(sel, 4, 64);
            acc[0] = ((lane & 4) ? hi : lo) + got;
        }
        acc[0] += movdpp<0x128>(acc[0]);  // xor8 via row_ror:8
        acc[0] = xorsum16(acc[0]);        // xor16 via permlane16_swap
        acc[0] = xorsum32(acc[0]);        // xor32 via permlane32_swap

        // combo layout within each 4-lane group (quad base):
        // +0: i(row rb), +1: g, +2: f, +3: o  (rb = (lane>>2)&1)
        float gi = movdpp<0x00>(acc[0]);  // quad bcast lane0
        float gg = movdpp<0x55>(acc[0]);  // quad bcast lane1
        float gf = movdpp<0xAA>(acc[0]);  // quad bcast lane2
        float go = movdpp<0xFF>(acc[0]);  // quad bcast lane3
        float i_ = sigm(gi + bi), f_ = sigm(gf + bf_), g_ = tanh_fast(gg + bg), o_ = sigm(go + bo);
        c_state = f_ * c_state + i_ * g_;
        float hval = o_ * tanh_fast(c_state);  // lanes 0-3: row0, lanes 4-7: row1 (replicated)

        // h1 (a row1 value) into lane 0 via row_ror:4
        float h1 = movdpp<0x124>(hval);
        if (lane == 0) {
            unsigned long long v = ((unsigned long long)packf16(hval, h1) << 32) | (uint32_t)s;
            ASTORE(&hbuf[((s & 1) << 10) + b * 4 + q], v);
            if (s == 8192) { hf32[hb + 2 * q] = hval; hf32[hb + 2 * q + 1] = h1; }
        }
    }
}

// ---------------- kernel 2: pred = h_last @ W_lin^T + b_lin ----------------
__global__ __launch_bounds__(256) void final_linear(const float* __restrict__ hf,
                                                    const float* __restrict__ Wlin,
                                                    const float* __restrict__ blin,
                                                    float* __restrict__ out) {
    const int row = blockIdx.x * 4 + (threadIdx.x >> 6);
    const int lane = threadIdx.x & 63;
    float acc = 0.f;
#pragma unroll
    for (int it = 0; it < 8; it++) {
        int c = it * 256 + lane * 4;
        float4 wv = *(const float4*)&Wlin[(size_t)row * 2048 + c];
        float4 hv = *(const float4*)&hf[c];
        acc += wv.x * hv.x + wv.y * hv.y + wv.z * hv.z + wv.w * hv.w;
    }
#pragma unroll
    for (int off = 32; off; off >>= 1) acc += __shfl_xor(acc, off, 64);
    if (lane == 0) out[row] = acc + blin[row];
}

// ---------------- launch ----------------
extern "C" void kernel_launch(void* const* d_in, const int* in_sizes, int n_in,
                              void* d_out, int out_size, void* d_ws, size_t ws_size,
                              hipStream_t stream) {
    const float* seq  = (const float*)d_in[0];
    const float* Wih  = (const float*)d_in[1];
    const float* Whh  = (const float*)d_in[2];
    const float* bih  = (const float*)d_in[3];
    const float* bhh  = (const float*)d_in[4];
    const float* h0   = (const float*)d_in[5];
    const float* c0   = (const float*)d_in[6];
    const float* Wlin = (const float*)d_in[7];
    const float* blin = (const float*)d_in[8];
    float* out = (float*)d_out;

    char* ws = (char*)d_ws;
    unsigned long long* hbuf = (unsigned long long*)ws;  // 2*1024*8 = 16 KiB
    float* hf32 = (float*)(ws + 16384);                  // 8 KiB

    init_hbuf<<<8, 256, 0, stream>>>(hbuf);
    lstm_persist<<<256, 256, 0, stream>>>(seq, Wih, Whh, bih, bhh, h0, c0, hbuf, hf32);
    final_linear<<<128, 256, 0, stream>>>(hf32, Wlin, blin, out);
}